// Round 1
// baseline (1926.121 us; speedup 1.0000x reference)
//
#include <hip/hip_runtime.h>
#include <hip/hip_fp16.h>

#define N_NODES 50000
#define N_EDGES 400000
#define NCLS 4
#define HID 32
#define HI 36                        // HID + IN_DIM
#define ROWS_P (N_NODES * NCLS)      // 200000 per-plane (n,c) rows
#define PADCAP 672000                // padded list capacity (E + ~3.5*N expected, 32-sigma safe)

// tanh(x) = 1 - 2/(exp(2x)+1); clamp avoids inf*0 NaN in the NR step.
__device__ __forceinline__ float fast_tanh(float x) {
    x = fminf(15.0f, fmaxf(-15.0f, x));
    float e = __expf(2.0f * x);
    float d = 1.0f + e;
    float r = __builtin_amdgcn_rcpf(d);
    r = r * (2.0f - d * r);   // one Newton step
    return 1.0f - 2.0f * r;
}

union F4H8 { float4 f4; __half2 h2[4]; };

// Per plane: m[n][c][0:32] = tanh(x @ inW + inb), m[n][c][32:36] = x (same across c)
__global__ void k_init(const float* __restrict__ x, const float* __restrict__ W,
                       const float* __restrict__ b, float* __restrict__ m) {
    unsigned t = blockIdx.x * 256 + threadIdx.x;
    if (t >= N_NODES * HI) return;
    unsigned idx = t % HI;
    unsigned n   = t / HI;
    float x0 = x[n * 4 + 0], x1 = x[n * 4 + 1];
    float x2 = x[n * 4 + 2], x3 = x[n * 4 + 3];
    float val;
    if (idx < 32) {
        float a = b[idx];
        a += x0 * W[idx] + x1 * W[32 + idx] + x2 * W[64 + idx] + x3 * W[96 + idx];
        val = fast_tanh(a);
    } else {
        val = (idx == 32) ? x0 : (idx == 33) ? x1 : (idx == 34) ? x2 : x3;
    }
    float* dst = m + (size_t)n * (NCLS * HI) + idx;
    dst[0] = val; dst[HI] = val; dst[2 * HI] = val; dst[3 * HI] = val;
}

// ---------------- CSR build (per plane, once) ----------------
__global__ void k_hist(const int* __restrict__ rowI, const int* __restrict__ colI,
                       int* __restrict__ inCnt, int* __restrict__ outCnt) {
    unsigned e = blockIdx.x * 256 + threadIdx.x;
    if (e >= N_EDGES) return;
    atomicAdd(&inCnt[colI[e]], 1);
    atomicAdd(&outCnt[rowI[e]], 1);
}

// Exclusive scan. block 0: raw in -> inOffRaw; block 1: padded-8 in -> pinOff;
// block 2: padded-8 out -> poutOff.
__global__ void k_scan(const int* __restrict__ inCnt, const int* __restrict__ outCnt,
                       int* __restrict__ inOffRaw, int* __restrict__ pinOff,
                       int* __restrict__ poutOff) {
    const int* cnt = (blockIdx.x == 2) ? outCnt : inCnt;
    int* off = (blockIdx.x == 0) ? inOffRaw : (blockIdx.x == 1) ? pinOff : poutOff;
    bool pad = blockIdx.x != 0;
    __shared__ int sh[16];
    __shared__ int carry;
    int tid = threadIdx.x;            // 1024
    int lane = tid & 63, wid = tid >> 6;
    if (tid == 0) carry = 0;
    __syncthreads();
    for (int base = 0; base < N_NODES; base += 1024) {
        int i = base + tid;
        int v = (i < N_NODES) ? cnt[i] : 0;
        if (pad) v = (v + 7) & ~7;
        int val = v;
#pragma unroll
        for (int d = 1; d < 64; d <<= 1) {
            int t = __shfl_up(val, d, 64);
            if (lane >= d) val += t;
        }
        if (lane == 63) sh[wid] = val;
        __syncthreads();
        if (tid < 16) {
            int s = sh[tid];
#pragma unroll
            for (int d = 1; d < 16; d <<= 1) {
                int t = __shfl_up(s, d, 16);
                if (tid >= d) s += t;
            }
            sh[tid] = s;
        }
        __syncthreads();
        int waveOff = (wid == 0) ? 0 : sh[wid - 1];
        int incl = val + waveOff + carry;
        if (i < N_NODES) off[i] = incl - v;
        __syncthreads();
        if (tid == 1023) carry = incl;
        __syncthreads();
    }
    if (tid == 0) off[N_NODES] = carry;
}

// Dense in-CSR entry for k_edge: inL2[dense]=(row|col<<16, piP), poPA[dense]=poP,
// eArr[dense]=e. Padded gather arrays: inPrt[piP]=row, outPrt[poP]=col
// (pad slots stay 0 from the per-plane memset).
__global__ void k_fill(const int* __restrict__ rowI, const int* __restrict__ colI,
                       const int* __restrict__ inOffRaw, const int* __restrict__ pinOff,
                       const int* __restrict__ poutOff,
                       int* __restrict__ inCur, int* __restrict__ outCur,
                       int2* __restrict__ inL2, int* __restrict__ poPA,
                       int* __restrict__ eArr,
                       unsigned short* __restrict__ inPrt,
                       unsigned short* __restrict__ outPrt) {
    unsigned e = blockIdx.x * 256 + threadIdx.x;
    if (e >= N_EDGES) return;
    int r = rowI[e], cn = colI[e];
    int liIn  = atomicAdd(&inCur[cn], 1);
    int liOut = atomicAdd(&outCur[r], 1);
    int dense = inOffRaw[cn] + liIn;
    int piP   = pinOff[cn] + liIn;
    int poP   = poutOff[r] + liOut;
    inL2[dense] = make_int2(r | (cn << 16), piP);
    poPA[dense] = poP;
    eArr[dense] = (int)e;
    inPrt[piP]  = (unsigned short)r;
    outPrt[poP] = (unsigned short)cn;
}

// ---------------- per-iteration kernels ----------------

// Fused 5-plane LDS-staged GEMM (320 threads): block stages 32 contiguous m-rows
// into LDS, each thread owns one of 160 output cols (u|v|p|q|r, all fp16) with
// wcol[36] register-resident; 2 row-groups x 16 rows.
__global__ void k_gemm5(const float* __restrict__ m,
                        const float* __restrict__ eW1, const float* __restrict__ nW1,
                        __half* __restrict__ u, __half* __restrict__ v,
                        __half* __restrict__ p, __half* __restrict__ q,
                        __half* __restrict__ r) {
    constexpr int RPB = 32;
    __shared__ float sm[RPB * HI];        // 4.6 KB
    unsigned tid = threadIdx.x;           // 320
    unsigned r0  = blockIdx.x * RPB;
    {
        const float4* gsrc = reinterpret_cast<const float4*>(m + (size_t)r0 * HI);
        float4* ldst = reinterpret_cast<float4*>(sm);
        for (unsigned i = tid; i < RPB * HI / 4; i += 320) ldst[i] = gsrc[i];
    }
    unsigned o = tid % 160, grp = tid / 160;   // grp in {0,1}
    unsigned sub = o >> 5, oo = o & 31;
    const float* W = (sub == 0) ? eW1 : (sub == 1) ? eW1 + 36 * 32 :
                     (sub == 2) ? nW1 : (sub == 3) ? nW1 + 36 * 32 : nW1 + 72 * 32;
    __half* dsth   = (sub == 0) ? u : (sub == 1) ? v : (sub == 2) ? p :
                     (sub == 3) ? q : r;
    float wcol[36];
#pragma unroll
    for (int k = 0; k < 36; ++k) wcol[k] = W[k * 32 + oo];
    __syncthreads();
#pragma unroll
    for (int i = 0; i < 16; ++i) {
        unsigned rloc = grp * 16 + i;
        const float4* mv4 = reinterpret_cast<const float4*>(sm + rloc * HI);
        float acc = 0.f;
#pragma unroll
        for (int t = 0; t < 9; ++t) {
            float4 mv = mv4[t];
            acc += mv.x * wcol[4 * t + 0];
            acc += mv.y * wcol[4 * t + 1];
            acc += mv.z * wcol[4 * t + 2];
            acc += mv.w * wcol[4 * t + 3];
        }
        dsth[(size_t)(r0 + rloc) * 32 + oo] = __float2half_rn(acc);
    }
}

// Final-pass projection: u|v only (LDS-staged, 256 threads).
__global__ void k_gemm2(const float* __restrict__ m, const float* __restrict__ W0,
                        const float* __restrict__ W1,
                        __half* __restrict__ o0, __half* __restrict__ o1) {
    constexpr int RPB = 32;
    __shared__ float sm[RPB * HI];
    unsigned tid = threadIdx.x;
    unsigned r0  = blockIdx.x * RPB;
    {
        const float4* gsrc = reinterpret_cast<const float4*>(m + (size_t)r0 * HI);
        float4* ldst = reinterpret_cast<float4*>(sm);
        for (unsigned i = tid; i < RPB * HI / 4; i += 256) ldst[i] = gsrc[i];
    }
    unsigned o = tid % 64, grp = tid / 64;     // 4 row-groups of 8
    unsigned sub = o >> 5, oo = o & 31;
    const float* W = sub ? W1 : W0;
    __half* dst    = sub ? o1 : o0;
    float wcol[36];
#pragma unroll
    for (int k = 0; k < 36; ++k) wcol[k] = W[k * 32 + oo];
    __syncthreads();
#pragma unroll
    for (int i = 0; i < 8; ++i) {
        unsigned rloc = grp * 8 + i;
        const float4* mv4 = reinterpret_cast<const float4*>(sm + rloc * HI);
        float acc = 0.f;
#pragma unroll
        for (int t = 0; t < 9; ++t) {
            float4 mv = mv4[t];
            acc += mv.x * wcol[4 * t + 0];
            acc += mv.y * wcol[4 * t + 1];
            acc += mv.z * wcol[4 * t + 2];
            acc += mv.w * wcol[4 * t + 3];
        }
        dst[(size_t)(r0 + rloc) * 32 + oo] = __float2half_rn(acc);
    }
}

// Edges in in-CSR order (grouped by col -> u side L1-resident).
// Per (idx,c): s = tanh(sum_o tanh(u[col]+v[row]+b1)*w2 + b2); softmax over c (4 lanes).
template <bool FINAL>
__global__ void k_edge(const int2* __restrict__ inL2, const int* __restrict__ poPA,
                       const int* __restrict__ eArr,
                       const __half* __restrict__ u, const __half* __restrict__ v,
                       const float* __restrict__ b1, const float* __restrict__ w2,
                       const float* __restrict__ b2,
                       __half* __restrict__ eaIn, __half* __restrict__ eaOut,
                       float* __restrict__ dst) {
    unsigned g   = blockIdx.x * 256 + threadIdx.x;   // exact grid: E*4
    unsigned c   = g & 3;
    unsigned idx = g >> 2;
    int2 ent = inL2[idx];
    unsigned rc  = (unsigned)ent.x;
    unsigned row = rc & 0xFFFFu, col = rc >> 16;
    const float4* u4 = reinterpret_cast<const float4*>(u + (col * 4 + c) * 32);
    const float4* v4 = reinterpret_cast<const float4*>(v + (row * 4 + c) * 32);
    float t2 = b2[0];
#pragma unroll
    for (int i = 0; i < 4; ++i) {          // 4 x (16B = 8 halves)
        F4H8 U, V; U.f4 = u4[i]; V.f4 = v4[i];
#pragma unroll
        for (int jj = 0; jj < 4; ++jj) {
            float2 uf = __half22float2(U.h2[jj]);
            float2 vf = __half22float2(V.h2[jj]);
            int o = i * 8 + jj * 2;
            t2 += fast_tanh(uf.x + vf.x + b1[o])     * w2[o];
            t2 += fast_tanh(uf.y + vf.y + b1[o + 1]) * w2[o + 1];
        }
    }
    float s  = fast_tanh(t2);
    float m1 = fmaxf(s, __shfl_xor(s, 1, 4));
    float mx = fmaxf(m1, __shfl_xor(m1, 2, 4));
    float ex = __expf(s - mx);
    float sm = ex + __shfl_xor(ex, 1, 4);
    sm = sm + __shfl_xor(sm, 2, 4);
    float val = ex / sm;
    if (FINAL) {
        dst[(unsigned)eArr[idx] * 4 + c] = val;
    } else {
        __half hv = __float2half_rn(val);
        eaIn[(unsigned)ent.y * 4 + c] = hv;
        eaOut[(unsigned)poPA[idx] * 4 + c] = hv;
    }
}

// Node net, wave-per-node. Gather phase: lane = (g,j), g=lane>>4 selects one of
// 4 edges in flight, j=lane&15 owns a 16B octet (halves 8j..8j+7) of the 256B
// p/q row -> one dwordx4 per 4 edges (was 2B/lane x 16 instrs per 8 edges).
// Partial sums per class-octet are combined with shfl_xor(16,32); epilogue
// W2 matmul reads t via __shfl from lanes 0..15 (all register indices static).
__global__ void k_node(float* __restrict__ m, const __half* __restrict__ rbuf,
                       const __half* __restrict__ p, const __half* __restrict__ q,
                       const __half* __restrict__ eaIn, const __half* __restrict__ eaOut,
                       const int* __restrict__ pinOff, const int* __restrict__ poutOff,
                       const unsigned short* __restrict__ inPrt,
                       const unsigned short* __restrict__ outPrt,
                       const float* __restrict__ nb1,
                       const float* __restrict__ nW2, const float* __restrict__ nb2) {
    __shared__ float sW2[32 * 32];
    unsigned tid = threadIdx.x;
    for (unsigned i = tid; i < 32 * 32; i += 256) sW2[i] = nW2[i];
    unsigned wv   = tid >> 6;            // wave 0..3 -> node
    unsigned lane = tid & 63;
    unsigned g  = lane >> 4;             // edge subgroup 0..3
    unsigned j  = lane & 15;             // dim octet: global half offs 8j..8j+7
    unsigned cj = j >> 2;                // class owned by this octet
    unsigned n = blockIdx.x * 4 + wv;
    float acc[8];
#pragma unroll
    for (int i = 0; i < 8; ++i) acc[i] = 0.f;
    __syncthreads();   // sW2 staged (before any variable-length work)
    {   // in-gather (padded multiple of 8 -> two 4-edge rounds per batch;
        // pad slots have prt=0, ea=0 so they contribute 0)
        int b1i = pinOff[n + 1];
        for (int b = pinOff[n]; b < b1i; b += 8) {
            unsigned e0 = (unsigned)b + g, e1 = (unsigned)b + 4 + g;
            unsigned prt0 = inPrt[e0], prt1 = inPrt[e1];
            float a0 = __half2float(eaIn[e0 * 4 + cj]);
            float a1 = __half2float(eaIn[e1 * 4 + cj]);
            F4H8 P0, P1;
            P0.f4 = reinterpret_cast<const float4*>(p + prt0 * 128u)[j];
            P1.f4 = reinterpret_cast<const float4*>(p + prt1 * 128u)[j];
#pragma unroll
            for (int h = 0; h < 4; ++h) {
                float2 f0 = __half22float2(P0.h2[h]);
                float2 f1 = __half22float2(P1.h2[h]);
                acc[2 * h]     += a0 * f0.x + a1 * f1.x;
                acc[2 * h + 1] += a0 * f0.y + a1 * f1.y;
            }
        }
    }
    {   // out-gather
        int b1o = poutOff[n + 1];
        for (int b = poutOff[n]; b < b1o; b += 8) {
            unsigned e0 = (unsigned)b + g, e1 = (unsigned)b + 4 + g;
            unsigned prt0 = outPrt[e0], prt1 = outPrt[e1];
            float a0 = __half2float(eaOut[e0 * 4 + cj]);
            float a1 = __half2float(eaOut[e1 * 4 + cj]);
            F4H8 P0, P1;
            P0.f4 = reinterpret_cast<const float4*>(q + prt0 * 128u)[j];
            P1.f4 = reinterpret_cast<const float4*>(q + prt1 * 128u)[j];
#pragma unroll
            for (int h = 0; h < 4; ++h) {
                float2 f0 = __half22float2(P0.h2[h]);
                float2 f1 = __half22float2(P1.h2[h]);
                acc[2 * h]     += a0 * f0.x + a1 * f1.x;
                acc[2 * h + 1] += a0 * f0.y + a1 * f1.y;
            }
        }
    }
    // combine the 4 edge-subgroups (sum over g)
#pragma unroll
    for (int i = 0; i < 8; ++i) {
        acc[i] += __shfl_xor(acc[i], 16, 64);
        acc[i] += __shfl_xor(acc[i], 32, 64);
    }
    // base (rbuf + b1) and tanh -> t[8] for dims 8j..8j+7 (class cj, k = 8*(j&3)+m)
    F4H8 R; R.f4 = reinterpret_cast<const float4*>(rbuf + (size_t)n * 128)[j];
    float t[8];
#pragma unroll
    for (int h = 0; h < 4; ++h) {
        float2 rf = __half22float2(R.h2[h]);
        unsigned k0 = (j & 3) * 8 + 2 * h;
        t[2 * h]     = fast_tanh(acc[2 * h]     + rf.x + nb1[k0]);
        t[2 * h + 1] = fast_tanh(acc[2 * h + 1] + rf.y + nb1[k0 + 1]);
    }
    // W2 matmul: lane computes outputs (c2,k) and (c2+2,k).
    // t(class c, dim kk) lives in lane c*4 + (kk>>3), register element kk&7.
    unsigned c2 = lane >> 5, k = lane & 31;
    float hh0 = nb2[k], hh1 = hh0;
#pragma unroll
    for (int kk = 0; kk < 32; ++kk) {
        float w = sW2[kk * 32 + k];
        float s0 = __shfl(t[kk & 7], (int)(c2 * 4 + (kk >> 3)), 64);
        float s1 = __shfl(t[kk & 7], (int)((c2 + 2) * 4 + (kk >> 3)), 64);
        hh0 += s0 * w;
        hh1 += s1 * w;
    }
    m[((size_t)n * 4 + c2) * HI + k]     = fast_tanh(hh0);
    m[((size_t)n * 4 + c2 + 2) * HI + k] = fast_tanh(hh1);
}

extern "C" void kernel_launch(void* const* d_in, const int* in_sizes, int n_in,
                              void* d_out, int out_size, void* d_ws, size_t ws_size,
                              hipStream_t stream) {
    const float* x   = (const float*)d_in[0];
    const int*   ei  = (const int*)d_in[1];
    const float* inW = (const float*)d_in[2];
    const float* inb = (const float*)d_in[3];
    const float* eW1 = (const float*)d_in[4];
    const float* eb1 = (const float*)d_in[5];
    const float* eW2 = (const float*)d_in[6];
    const float* eb2 = (const float*)d_in[7];
    const float* nW1 = (const float*)d_in[8];
    const float* nb1 = (const float*)d_in[9];
    const float* nW2 = (const float*)d_in[10];
    const float* nb2 = (const float*)d_in[11];
    float* out = (float*)d_out;

    // Workspace (~110 MB): m 28.8 | u,v,p,q fp16 51.2 | r fp16 12.8 |
    // eaIn/eaOut fp16 10.8 | inL2 3.2 | poPA 1.6 | eArr 1.6 | prt u16 2.7 | offs ~1.0
    float*  m     = (float*)d_ws;
    __half* u     = (__half*)(m + (size_t)ROWS_P * HI);
    __half* v     = u + (size_t)ROWS_P * 32;
    __half* p     = v + (size_t)ROWS_P * 32;
    __half* q     = p + (size_t)ROWS_P * 32;
    __half* rbuf  = q + (size_t)ROWS_P * 32;
    __half* eaIn  = rbuf + (size_t)ROWS_P * 32;
    __half* eaOut = eaIn + (size_t)PADCAP * 4;
    int2*   inL2  = (int2*)(eaOut + (size_t)PADCAP * 4);
    int*    poPA  = (int*)(inL2 + N_EDGES);
    int*    eArr  = poPA + N_EDGES;
    unsigned short* inPrt  = (unsigned short*)(eArr + N_EDGES);
    unsigned short* outPrt = inPrt + PADCAP;
    int*    inOffRaw = (int*)(outPrt + PADCAP);
    int*    pinOff   = inOffRaw + (N_NODES + 1);
    int*    poutOff  = pinOff + (N_NODES + 1);
    int*    inCur    = poutOff + (N_NODES + 1);
    int*    outCur   = inCur + N_NODES;

    const int gridE = (N_EDGES + 255) / 256;

    for (int j = 0; j < 3; ++j) {
        const int*   rowI = ei + (size_t)j * 2 * N_EDGES;
        const int*   colI = rowI + N_EDGES;
        const float* eW1j = eW1 + j * 72 * 32;
        const float* eb1j = eb1 + j * 32;
        const float* eW2j = eW2 + j * 32;
        const float* eb2j = eb2 + j;
        const float* nW1j = nW1 + j * 108 * 32;
        const float* nb1j = nb1 + j * 32;
        const float* nW2j = nW2 + j * 1024;
        const float* nb2j = nb2 + j * 32;

        // CSR build (padded)
        hipMemsetAsync(inCur, 0, 2 * N_NODES * sizeof(int), stream);
        k_hist<<<gridE, 256, 0, stream>>>(rowI, colI, inCur, outCur);
        k_scan<<<3, 1024, 0, stream>>>(inCur, outCur, inOffRaw, pinOff, poutOff);
        hipMemsetAsync(inCur, 0, 2 * N_NODES * sizeof(int), stream);
        hipMemsetAsync(inPrt, 0, 2 * (size_t)PADCAP * sizeof(unsigned short), stream);
        hipMemsetAsync(eaIn, 0, 2 * (size_t)PADCAP * 4 * sizeof(__half), stream);
        k_fill<<<gridE, 256, 0, stream>>>(rowI, colI, inOffRaw, pinOff, poutOff,
                                          inCur, outCur, inL2, poPA, eArr, inPrt, outPrt);

        k_init<<<(N_NODES * HI + 255) / 256, 256, 0, stream>>>(
            x + (size_t)j * N_NODES * 4, inW + j * 128, inb + j * 32, m);

        for (int it = 0; it < 3; ++it) {
            k_gemm5<<<ROWS_P / 32, 320, 0, stream>>>(m, eW1j, nW1j, u, v, p, q, rbuf);
            k_edge<false><<<N_EDGES * 4 / 256, 256, 0, stream>>>(
                inL2, poPA, eArr, u, v, eb1j, eW2j, eb2j, eaIn, eaOut, nullptr);
            k_node<<<N_NODES / 4, 256, 0, stream>>>(m, rbuf, p, q, eaIn, eaOut,
                                                    pinOff, poutOff, inPrt, outPrt,
                                                    nb1j, nW2j, nb2j);
        }
        k_gemm2<<<ROWS_P / 32, 256, 0, stream>>>(m, eW1j, eW1j + 36 * 32, u, v);
        k_edge<true><<<N_EDGES * 4 / 256, 256, 0, stream>>>(
            inL2, poPA, eArr, u, v, eb1j, eW2j, eb2j, nullptr, nullptr,
            out + (size_t)j * N_EDGES * 4);
    }
}

// Round 2
// 1800.848 us; speedup vs baseline: 1.0696x; 1.0696x over previous
//
#include <hip/hip_runtime.h>
#include <hip/hip_fp16.h>

#define N_NODES 50000
#define N_EDGES 400000
#define NCLS 4
#define HID 32
#define HI 36                        // HID + IN_DIM
#define ROWS_P (N_NODES * NCLS)      // 200000 per-plane (n,c) rows
#define PADCAP 672000                // padded list capacity (E + ~3.5*N expected, 32-sigma safe)

// tanh(x) = 1 - 2/(exp(2x)+1); clamp avoids inf*0 NaN in the NR step.
__device__ __forceinline__ float fast_tanh(float x) {
    x = fminf(15.0f, fmaxf(-15.0f, x));
    float e = __expf(2.0f * x);
    float d = 1.0f + e;
    float r = __builtin_amdgcn_rcpf(d);
    r = r * (2.0f - d * r);   // one Newton step
    return 1.0f - 2.0f * r;
}

union F4H8 { float4 f4; __half2 h2[4]; };

// Per plane: m[n][c][0:32] = tanh(x @ inW + inb), m[n][c][32:36] = x (same across c)
__global__ void k_init(const float* __restrict__ x, const float* __restrict__ W,
                       const float* __restrict__ b, float* __restrict__ m) {
    unsigned t = blockIdx.x * 256 + threadIdx.x;
    if (t >= N_NODES * HI) return;
    unsigned idx = t % HI;
    unsigned n   = t / HI;
    float x0 = x[n * 4 + 0], x1 = x[n * 4 + 1];
    float x2 = x[n * 4 + 2], x3 = x[n * 4 + 3];
    float val;
    if (idx < 32) {
        float a = b[idx];
        a += x0 * W[idx] + x1 * W[32 + idx] + x2 * W[64 + idx] + x3 * W[96 + idx];
        val = fast_tanh(a);
    } else {
        val = (idx == 32) ? x0 : (idx == 33) ? x1 : (idx == 34) ? x2 : x3;
    }
    float* dst = m + (size_t)n * (NCLS * HI) + idx;
    dst[0] = val; dst[HI] = val; dst[2 * HI] = val; dst[3 * HI] = val;
}

// ---------------- CSR build (per plane, once) ----------------
__global__ void k_hist(const int* __restrict__ rowI, const int* __restrict__ colI,
                       int* __restrict__ inCnt, int* __restrict__ outCnt) {
    unsigned e = blockIdx.x * 256 + threadIdx.x;
    if (e >= N_EDGES) return;
    atomicAdd(&inCnt[colI[e]], 1);
    atomicAdd(&outCnt[rowI[e]], 1);
}

// Exclusive scan. block 0: raw in -> inOffRaw; block 1: padded-8 in -> pinOff;
// block 2: padded-8 out -> poutOff.
__global__ void k_scan(const int* __restrict__ inCnt, const int* __restrict__ outCnt,
                       int* __restrict__ inOffRaw, int* __restrict__ pinOff,
                       int* __restrict__ poutOff) {
    const int* cnt = (blockIdx.x == 2) ? outCnt : inCnt;
    int* off = (blockIdx.x == 0) ? inOffRaw : (blockIdx.x == 1) ? pinOff : poutOff;
    bool pad = blockIdx.x != 0;
    __shared__ int sh[16];
    __shared__ int carry;
    int tid = threadIdx.x;            // 1024
    int lane = tid & 63, wid = tid >> 6;
    if (tid == 0) carry = 0;
    __syncthreads();
    for (int base = 0; base < N_NODES; base += 1024) {
        int i = base + tid;
        int v = (i < N_NODES) ? cnt[i] : 0;
        if (pad) v = (v + 7) & ~7;
        int val = v;
#pragma unroll
        for (int d = 1; d < 64; d <<= 1) {
            int t = __shfl_up(val, d, 64);
            if (lane >= d) val += t;
        }
        if (lane == 63) sh[wid] = val;
        __syncthreads();
        if (tid < 16) {
            int s = sh[tid];
#pragma unroll
            for (int d = 1; d < 16; d <<= 1) {
                int t = __shfl_up(s, d, 16);
                if (tid >= d) s += t;
            }
            sh[tid] = s;
        }
        __syncthreads();
        int waveOff = (wid == 0) ? 0 : sh[wid - 1];
        int incl = val + waveOff + carry;
        if (i < N_NODES) off[i] = incl - v;
        __syncthreads();
        if (tid == 1023) carry = incl;
        __syncthreads();
    }
    if (tid == 0) off[N_NODES] = carry;
}

// Dense in-CSR entry for k_edge: inL2[dense]=(row|col<<16, piP), poPA[dense]=poP,
// eArr[dense]=e. Padded gather arrays: inPrt[piP]=row, outPrt[poP]=col
// (pad slots stay 0 from the per-plane memset).
__global__ void k_fill(const int* __restrict__ rowI, const int* __restrict__ colI,
                       const int* __restrict__ inOffRaw, const int* __restrict__ pinOff,
                       const int* __restrict__ poutOff,
                       int* __restrict__ inCur, int* __restrict__ outCur,
                       int2* __restrict__ inL2, int* __restrict__ poPA,
                       int* __restrict__ eArr,
                       unsigned short* __restrict__ inPrt,
                       unsigned short* __restrict__ outPrt) {
    unsigned e = blockIdx.x * 256 + threadIdx.x;
    if (e >= N_EDGES) return;
    int r = rowI[e], cn = colI[e];
    int liIn  = atomicAdd(&inCur[cn], 1);
    int liOut = atomicAdd(&outCur[r], 1);
    int dense = inOffRaw[cn] + liIn;
    int piP   = pinOff[cn] + liIn;
    int poP   = poutOff[r] + liOut;
    inL2[dense] = make_int2(r | (cn << 16), piP);
    poPA[dense] = poP;
    eArr[dense] = (int)e;
    inPrt[piP]  = (unsigned short)r;
    outPrt[poP] = (unsigned short)cn;
}

// ---------------- per-iteration kernels ----------------

// Fused 5-plane LDS-staged GEMM (320 threads): block stages 32 contiguous m-rows
// into LDS, each thread owns one of 160 output cols (u|v|p|q|r, all fp16) with
// wcol[36] register-resident; 2 row-groups x 16 rows.
__global__ void k_gemm5(const float* __restrict__ m,
                        const float* __restrict__ eW1, const float* __restrict__ nW1,
                        __half* __restrict__ u, __half* __restrict__ v,
                        __half* __restrict__ p, __half* __restrict__ q,
                        __half* __restrict__ r) {
    constexpr int RPB = 32;
    __shared__ float sm[RPB * HI];        // 4.6 KB
    unsigned tid = threadIdx.x;           // 320
    unsigned r0  = blockIdx.x * RPB;
    {
        const float4* gsrc = reinterpret_cast<const float4*>(m + (size_t)r0 * HI);
        float4* ldst = reinterpret_cast<float4*>(sm);
        for (unsigned i = tid; i < RPB * HI / 4; i += 320) ldst[i] = gsrc[i];
    }
    unsigned o = tid % 160, grp = tid / 160;   // grp in {0,1}
    unsigned sub = o >> 5, oo = o & 31;
    const float* W = (sub == 0) ? eW1 : (sub == 1) ? eW1 + 36 * 32 :
                     (sub == 2) ? nW1 : (sub == 3) ? nW1 + 36 * 32 : nW1 + 72 * 32;
    __half* dsth   = (sub == 0) ? u : (sub == 1) ? v : (sub == 2) ? p :
                     (sub == 3) ? q : r;
    float wcol[36];
#pragma unroll
    for (int k = 0; k < 36; ++k) wcol[k] = W[k * 32 + oo];
    __syncthreads();
#pragma unroll
    for (int i = 0; i < 16; ++i) {
        unsigned rloc = grp * 16 + i;
        const float4* mv4 = reinterpret_cast<const float4*>(sm + rloc * HI);
        float acc = 0.f;
#pragma unroll
        for (int t = 0; t < 9; ++t) {
            float4 mv = mv4[t];
            acc += mv.x * wcol[4 * t + 0];
            acc += mv.y * wcol[4 * t + 1];
            acc += mv.z * wcol[4 * t + 2];
            acc += mv.w * wcol[4 * t + 3];
        }
        dsth[(size_t)(r0 + rloc) * 32 + oo] = __float2half_rn(acc);
    }
}

// Final-pass projection: u|v only (LDS-staged, 256 threads).
__global__ void k_gemm2(const float* __restrict__ m, const float* __restrict__ W0,
                        const float* __restrict__ W1,
                        __half* __restrict__ o0, __half* __restrict__ o1) {
    constexpr int RPB = 32;
    __shared__ float sm[RPB * HI];
    unsigned tid = threadIdx.x;
    unsigned r0  = blockIdx.x * RPB;
    {
        const float4* gsrc = reinterpret_cast<const float4*>(m + (size_t)r0 * HI);
        float4* ldst = reinterpret_cast<float4*>(sm);
        for (unsigned i = tid; i < RPB * HI / 4; i += 256) ldst[i] = gsrc[i];
    }
    unsigned o = tid % 64, grp = tid / 64;     // 4 row-groups of 8
    unsigned sub = o >> 5, oo = o & 31;
    const float* W = sub ? W1 : W0;
    __half* dst    = sub ? o1 : o0;
    float wcol[36];
#pragma unroll
    for (int k = 0; k < 36; ++k) wcol[k] = W[k * 32 + oo];
    __syncthreads();
#pragma unroll
    for (int i = 0; i < 8; ++i) {
        unsigned rloc = grp * 8 + i;
        const float4* mv4 = reinterpret_cast<const float4*>(sm + rloc * HI);
        float acc = 0.f;
#pragma unroll
        for (int t = 0; t < 9; ++t) {
            float4 mv = mv4[t];
            acc += mv.x * wcol[4 * t + 0];
            acc += mv.y * wcol[4 * t + 1];
            acc += mv.z * wcol[4 * t + 2];
            acc += mv.w * wcol[4 * t + 3];
        }
        dst[(size_t)(r0 + rloc) * 32 + oo] = __float2half_rn(acc);
    }
}

// Edges in in-CSR order (grouped by col -> u side L1-resident).
// Per (idx,c): s = tanh(sum_o tanh(u[col]+v[row]+b1)*w2 + b2); softmax over c (4 lanes).
// ea outputs stored TRANSPOSED: ea[c*PADCAP + slot] (16B-contiguous per class for k_node).
template <bool FINAL>
__global__ void k_edge(const int2* __restrict__ inL2, const int* __restrict__ poPA,
                       const int* __restrict__ eArr,
                       const __half* __restrict__ u, const __half* __restrict__ v,
                       const float* __restrict__ b1, const float* __restrict__ w2,
                       const float* __restrict__ b2,
                       __half* __restrict__ eaIn, __half* __restrict__ eaOut,
                       float* __restrict__ dst) {
    unsigned g   = blockIdx.x * 256 + threadIdx.x;   // exact grid: E*4
    unsigned c   = g & 3;
    unsigned idx = g >> 2;
    int2 ent = inL2[idx];
    unsigned rc  = (unsigned)ent.x;
    unsigned row = rc & 0xFFFFu, col = rc >> 16;
    const float4* u4 = reinterpret_cast<const float4*>(u + (col * 4 + c) * 32);
    const float4* v4 = reinterpret_cast<const float4*>(v + (row * 4 + c) * 32);
    float t2 = b2[0];
#pragma unroll
    for (int i = 0; i < 4; ++i) {          // 4 x (16B = 8 halves)
        F4H8 U, V; U.f4 = u4[i]; V.f4 = v4[i];
#pragma unroll
        for (int jj = 0; jj < 4; ++jj) {
            float2 uf = __half22float2(U.h2[jj]);
            float2 vf = __half22float2(V.h2[jj]);
            int o = i * 8 + jj * 2;
            t2 += fast_tanh(uf.x + vf.x + b1[o])     * w2[o];
            t2 += fast_tanh(uf.y + vf.y + b1[o + 1]) * w2[o + 1];
        }
    }
    float s  = fast_tanh(t2);
    float m1 = fmaxf(s, __shfl_xor(s, 1, 4));
    float mx = fmaxf(m1, __shfl_xor(m1, 2, 4));
    float ex = __expf(s - mx);
    float sm = ex + __shfl_xor(ex, 1, 4);
    sm = sm + __shfl_xor(sm, 2, 4);
    float val = ex / sm;
    if (FINAL) {
        dst[(unsigned)eArr[idx] * 4 + c] = val;
    } else {
        __half hv = __float2half_rn(val);
        eaIn[(size_t)c * PADCAP + (unsigned)ent.y] = hv;
        eaOut[(size_t)c * PADCAP + (unsigned)poPA[idx]] = hv;
    }
}

// Node net, ONE WAVE PER NODE (block=64). n = blockIdx.x is an SGPR -> offset
// and prt loads scalarize; gathers keep the proven 2x128B-coalesced-per-edge
// shape. Batch metadata vectorized (prt: one uint4 of 8xu16; ea: transposed,
// one 16B load per class). Out-loop's first batch pre-issued before the
// in-loop; in-loop prefetches batch b+8. No LDS, no barrier (nW2 read direct,
// L1-resident 4KB).
__global__ void __launch_bounds__(64, 4)
k_node(float* __restrict__ m, const __half* __restrict__ rbuf,
       const __half* __restrict__ p, const __half* __restrict__ q,
       const __half* __restrict__ eaInT, const __half* __restrict__ eaOutT,
       const int* __restrict__ pinOff, const int* __restrict__ poutOff,
       const unsigned short* __restrict__ inPrt,
       const unsigned short* __restrict__ outPrt,
       const float* __restrict__ nb1,
       const float* __restrict__ nW2, const float* __restrict__ nb2) {
    unsigned lane = threadIdx.x;         // 64
    unsigned c2 = lane >> 5, k = lane & 31;
    unsigned n = blockIdx.x;
    unsigned gOff0 = c2 * 32 + k;
    unsigned gOff1 = gOff0 + 64;

    // independent loads first (issue early)
    float b1k = nb1[k];
    float h0 = __half2float(rbuf[((size_t)n * 4 + c2) * 32 + k]) + b1k;      // class c2
    float h1 = __half2float(rbuf[((size_t)n * 4 + c2 + 2) * 32 + k]) + b1k;  // class c2+2

    int bi0 = pinOff[n],  biE = pinOff[n + 1];
    int bo0 = poutOff[n], boE = poutOff[n + 1];
    __builtin_assume((bi0 & 7) == 0);
    __builtin_assume((bo0 & 7) == 0);

    auto accum = [&](const __half* __restrict__ base, uint4 prtv, uint4 e0v, uint4 e1v) {
        unsigned pr0 = prtv.x & 0xFFFFu, pr1 = prtv.x >> 16;
        unsigned pr2 = prtv.y & 0xFFFFu, pr3 = prtv.y >> 16;
        unsigned pr4 = prtv.z & 0xFFFFu, pr5 = prtv.z >> 16;
        unsigned pr6 = prtv.w & 0xFFFFu, pr7 = prtv.w >> 16;
        __half g0h[8], g1h[8];
        const __half* r0p = base + (size_t)pr0 * 128u; g0h[0] = r0p[gOff0]; g1h[0] = r0p[gOff1];
        const __half* r1p = base + (size_t)pr1 * 128u; g0h[1] = r1p[gOff0]; g1h[1] = r1p[gOff1];
        const __half* r2p = base + (size_t)pr2 * 128u; g0h[2] = r2p[gOff0]; g1h[2] = r2p[gOff1];
        const __half* r3p = base + (size_t)pr3 * 128u; g0h[3] = r3p[gOff0]; g1h[3] = r3p[gOff1];
        const __half* r4p = base + (size_t)pr4 * 128u; g0h[4] = r4p[gOff0]; g1h[4] = r4p[gOff1];
        const __half* r5p = base + (size_t)pr5 * 128u; g0h[5] = r5p[gOff0]; g1h[5] = r5p[gOff1];
        const __half* r6p = base + (size_t)pr6 * 128u; g0h[6] = r6p[gOff0]; g1h[6] = r6p[gOff1];
        const __half* r7p = base + (size_t)pr7 * 128u; g0h[7] = r7p[gOff0]; g1h[7] = r7p[gOff1];
        union { uint4 u4; __half2 h2[4]; } E0, E1;
        E0.u4 = e0v; E1.u4 = e1v;
#pragma unroll
        for (int ii = 0; ii < 4; ++ii) {
            float2 A0 = __half22float2(E0.h2[ii]);   // class c2, edges 2ii,2ii+1
            float2 A1 = __half22float2(E1.h2[ii]);   // class c2+2
            h0 += A0.x * __half2float(g0h[2 * ii]) + A0.y * __half2float(g0h[2 * ii + 1]);
            h1 += A1.x * __half2float(g1h[2 * ii]) + A1.y * __half2float(g1h[2 * ii + 1]);
        }
    };

    // pre-issue first OUT batch (hides its latency under the whole in-loop)
    uint4 oprt = {0, 0, 0, 0}, oe0 = {0, 0, 0, 0}, oe1 = {0, 0, 0, 0};
    if (bo0 < boE) {
        oprt = *(const uint4*)(outPrt + bo0);
        oe0  = *(const uint4*)(eaOutT + (size_t)c2 * PADCAP + bo0);
        oe1  = *(const uint4*)(eaOutT + (size_t)(c2 + 2) * PADCAP + bo0);
    }

    if (bi0 < biE) {
        uint4 cprt = *(const uint4*)(inPrt + bi0);
        uint4 ce0  = *(const uint4*)(eaInT + (size_t)c2 * PADCAP + bi0);
        uint4 ce1  = *(const uint4*)(eaInT + (size_t)(c2 + 2) * PADCAP + bi0);
        for (int b = bi0; b < biE; b += 8) {
            uint4 nprt = cprt, ne0 = ce0, ne1 = ce1;
            if (b + 8 < biE) {                       // prefetch next batch
                nprt = *(const uint4*)(inPrt + b + 8);
                ne0  = *(const uint4*)(eaInT + (size_t)c2 * PADCAP + b + 8);
                ne1  = *(const uint4*)(eaInT + (size_t)(c2 + 2) * PADCAP + b + 8);
            }
            accum(p, cprt, ce0, ce1);
            cprt = nprt; ce0 = ne0; ce1 = ne1;
        }
    }
    if (bo0 < boE) {
        uint4 cprt = oprt, ce0 = oe0, ce1 = oe1;     // already in flight
        for (int b = bo0; b < boE; b += 8) {
            uint4 nprt = cprt, ne0 = ce0, ne1 = ce1;
            if (b + 8 < boE) {
                nprt = *(const uint4*)(outPrt + b + 8);
                ne0  = *(const uint4*)(eaOutT + (size_t)c2 * PADCAP + b + 8);
                ne1  = *(const uint4*)(eaOutT + (size_t)(c2 + 2) * PADCAP + b + 8);
            }
            accum(q, cprt, ce0, ce1);
            cprt = nprt; ce0 = ne0; ce1 = ne1;
        }
    }

    float t0 = fast_tanh(h0);   // class c2, dim k (lane-local)
    float t1 = fast_tanh(h1);   // class c2+2, dim k
    float hh0 = nb2[k], hh1 = hh0;
#pragma unroll
    for (int kk = 0; kk < 32; ++kk) {
        float w = nW2[kk * 32 + k];                  // L1-resident broadcast
        float s0 = __shfl(t0, (int)(c2 * 32 + kk), 64);   // t(class c2, kk)
        float s1 = __shfl(t1, (int)(c2 * 32 + kk), 64);   // t(class c2+2, kk)
        hh0 += s0 * w;
        hh1 += s1 * w;
    }
    m[((size_t)n * 4 + c2) * HI + k]     = fast_tanh(hh0);
    m[((size_t)n * 4 + c2 + 2) * HI + k] = fast_tanh(hh1);
}

extern "C" void kernel_launch(void* const* d_in, const int* in_sizes, int n_in,
                              void* d_out, int out_size, void* d_ws, size_t ws_size,
                              hipStream_t stream) {
    const float* x   = (const float*)d_in[0];
    const int*   ei  = (const int*)d_in[1];
    const float* inW = (const float*)d_in[2];
    const float* inb = (const float*)d_in[3];
    const float* eW1 = (const float*)d_in[4];
    const float* eb1 = (const float*)d_in[5];
    const float* eW2 = (const float*)d_in[6];
    const float* eb2 = (const float*)d_in[7];
    const float* nW1 = (const float*)d_in[8];
    const float* nb1 = (const float*)d_in[9];
    const float* nW2 = (const float*)d_in[10];
    const float* nb2 = (const float*)d_in[11];
    float* out = (float*)d_out;

    // Workspace (~110 MB): m 28.8 | u,v,p,q fp16 51.2 | r fp16 12.8 |
    // eaIn/eaOut fp16 10.8 (transposed: 4 planes of PADCAP halves each) |
    // inL2 3.2 | poPA 1.6 | eArr 1.6 | prt u16 2.7 | offs ~1.0
    float*  m     = (float*)d_ws;
    __half* u     = (__half*)(m + (size_t)ROWS_P * HI);
    __half* v     = u + (size_t)ROWS_P * 32;
    __half* p     = v + (size_t)ROWS_P * 32;
    __half* q     = p + (size_t)ROWS_P * 32;
    __half* rbuf  = q + (size_t)ROWS_P * 32;
    __half* eaIn  = rbuf + (size_t)ROWS_P * 32;
    __half* eaOut = eaIn + (size_t)PADCAP * 4;
    int2*   inL2  = (int2*)(eaOut + (size_t)PADCAP * 4);
    int*    poPA  = (int*)(inL2 + N_EDGES);
    int*    eArr  = poPA + N_EDGES;
    unsigned short* inPrt  = (unsigned short*)(eArr + N_EDGES);
    unsigned short* outPrt = inPrt + PADCAP;
    int*    inOffRaw = (int*)(outPrt + PADCAP);
    int*    pinOff   = inOffRaw + (N_NODES + 1);
    int*    poutOff  = pinOff + (N_NODES + 1);
    int*    inCur    = poutOff + (N_NODES + 1);
    int*    outCur   = inCur + N_NODES;

    const int gridE = (N_EDGES + 255) / 256;

    for (int j = 0; j < 3; ++j) {
        const int*   rowI = ei + (size_t)j * 2 * N_EDGES;
        const int*   colI = rowI + N_EDGES;
        const float* eW1j = eW1 + j * 72 * 32;
        const float* eb1j = eb1 + j * 32;
        const float* eW2j = eW2 + j * 32;
        const float* eb2j = eb2 + j;
        const float* nW1j = nW1 + j * 108 * 32;
        const float* nb1j = nb1 + j * 32;
        const float* nW2j = nW2 + j * 1024;
        const float* nb2j = nb2 + j * 32;

        // CSR build (padded)
        hipMemsetAsync(inCur, 0, 2 * N_NODES * sizeof(int), stream);
        k_hist<<<gridE, 256, 0, stream>>>(rowI, colI, inCur, outCur);
        k_scan<<<3, 1024, 0, stream>>>(inCur, outCur, inOffRaw, pinOff, poutOff);
        hipMemsetAsync(inCur, 0, 2 * N_NODES * sizeof(int), stream);
        hipMemsetAsync(inPrt, 0, 2 * (size_t)PADCAP * sizeof(unsigned short), stream);
        hipMemsetAsync(eaIn, 0, 2 * (size_t)PADCAP * 4 * sizeof(__half), stream);
        k_fill<<<gridE, 256, 0, stream>>>(rowI, colI, inOffRaw, pinOff, poutOff,
                                          inCur, outCur, inL2, poPA, eArr, inPrt, outPrt);

        k_init<<<(N_NODES * HI + 255) / 256, 256, 0, stream>>>(
            x + (size_t)j * N_NODES * 4, inW + j * 128, inb + j * 32, m);

        for (int it = 0; it < 3; ++it) {
            k_gemm5<<<ROWS_P / 32, 320, 0, stream>>>(m, eW1j, nW1j, u, v, p, q, rbuf);
            k_edge<false><<<N_EDGES * 4 / 256, 256, 0, stream>>>(
                inL2, poPA, eArr, u, v, eb1j, eW2j, eb2j, eaIn, eaOut, nullptr);
            k_node<<<N_NODES, 64, 0, stream>>>(m, rbuf, p, q, eaIn, eaOut,
                                               pinOff, poutOff, inPrt, outPrt,
                                               nb1j, nW2j, nb2j);
        }
        k_gemm2<<<ROWS_P / 32, 256, 0, stream>>>(m, eW1j, eW1j + 36 * 32, u, v);
        k_edge<true><<<N_EDGES * 4 / 256, 256, 0, stream>>>(
            inL2, poPA, eArr, u, v, eb1j, eW2j, eb2j, nullptr, nullptr,
            out + (size_t)j * N_EDGES * 4);
    }
}

// Round 3
// 1702.765 us; speedup vs baseline: 1.1312x; 1.0576x over previous
//
#include <hip/hip_runtime.h>
#include <hip/hip_fp16.h>

#define N_NODES 50000
#define N_EDGES 400000
#define NCLS 4
#define HID 32
#define HI 36                        // HID + IN_DIM
#define ROWS_P (N_NODES * NCLS)      // 200000 per-plane (n,c) rows
#define PADCAP 672000                // padded list capacity (E + ~3.5*N expected, 32-sigma safe)
#define SLICES 8                     // XCD count (write-locality slicing)
#define BUCKS_PER_SLICE (N_NODES / SLICES)   // 6250

// tanh(x) = 1 - 2/(exp(2x)+1); clamp avoids inf*0 NaN in the NR step.
__device__ __forceinline__ float fast_tanh(float x) {
    x = fminf(15.0f, fmaxf(-15.0f, x));
    float e = __expf(2.0f * x);
    float d = 1.0f + e;
    float r = __builtin_amdgcn_rcpf(d);
    r = r * (2.0f - d * r);   // one Newton step
    return 1.0f - 2.0f * r;
}

union F4H8 { float4 f4; __half2 h2[4]; };

// Per plane: m[n][c][0:32] = tanh(x @ inW + inb), m[n][c][32:36] = x (same across c)
__global__ void k_init(const float* __restrict__ x, const float* __restrict__ W,
                       const float* __restrict__ b, float* __restrict__ m) {
    unsigned t = blockIdx.x * 256 + threadIdx.x;
    if (t >= N_NODES * HI) return;
    unsigned idx = t % HI;
    unsigned n   = t / HI;
    float x0 = x[n * 4 + 0], x1 = x[n * 4 + 1];
    float x2 = x[n * 4 + 2], x3 = x[n * 4 + 3];
    float val;
    if (idx < 32) {
        float a = b[idx];
        a += x0 * W[idx] + x1 * W[32 + idx] + x2 * W[64 + idx] + x3 * W[96 + idx];
        val = fast_tanh(a);
    } else {
        val = (idx == 32) ? x0 : (idx == 33) ? x1 : (idx == 34) ? x2 : x3;
    }
    float* dst = m + (size_t)n * (NCLS * HI) + idx;
    dst[0] = val; dst[HI] = val; dst[2 * HI] = val; dst[3 * HI] = val;
}

// ---------------- CSR build (per plane, once) ----------------
// Pass 1: single atomic pass; counters become counts, returned local indices
// stored packed (liIn | liOut<<16) in a contiguous temp (no amplification).
__global__ void k_pass1(const int* __restrict__ rowI, const int* __restrict__ colI,
                        int* __restrict__ inCnt, int* __restrict__ outCnt,
                        int* __restrict__ tmpLi) {
    unsigned e = blockIdx.x * 256 + threadIdx.x;
    if (e >= N_EDGES) return;
    int r = rowI[e], cn = colI[e];
    int liIn  = atomicAdd(&inCnt[cn], 1);
    int liOut = atomicAdd(&outCnt[r], 1);
    tmpLi[e] = liIn | (liOut << 16);
}

// Exclusive scan. block 0: raw in -> inOffRaw; block 1: padded-8 in -> pinOff;
// block 2: padded-8 out -> poutOff.
__global__ void k_scan(const int* __restrict__ inCnt, const int* __restrict__ outCnt,
                       int* __restrict__ inOffRaw, int* __restrict__ pinOff,
                       int* __restrict__ poutOff) {
    const int* cnt = (blockIdx.x == 2) ? outCnt : inCnt;
    int* off = (blockIdx.x == 0) ? inOffRaw : (blockIdx.x == 1) ? pinOff : poutOff;
    bool pad = blockIdx.x != 0;
    __shared__ int sh[16];
    __shared__ int carry;
    int tid = threadIdx.x;            // 1024
    int lane = tid & 63, wid = tid >> 6;
    if (tid == 0) carry = 0;
    __syncthreads();
    for (int base = 0; base < N_NODES; base += 1024) {
        int i = base + tid;
        int v = (i < N_NODES) ? cnt[i] : 0;
        if (pad) v = (v + 7) & ~7;
        int val = v;
#pragma unroll
        for (int d = 1; d < 64; d <<= 1) {
            int t = __shfl_up(val, d, 64);
            if (lane >= d) val += t;
        }
        if (lane == 63) sh[wid] = val;
        __syncthreads();
        if (tid < 16) {
            int s = sh[tid];
#pragma unroll
            for (int d = 1; d < 16; d <<= 1) {
                int t = __shfl_up(s, d, 16);
                if (tid >= d) s += t;
            }
            sh[tid] = s;
        }
        __syncthreads();
        int waveOff = (wid == 0) ? 0 : sh[wid - 1];
        int incl = val + waveOff + carry;
        if (i < N_NODES) off[i] = incl - v;
        __syncthreads();
        if (tid == 1023) carry = incl;
        __syncthreads();
    }
    if (tid == 0) off[N_NODES] = carry;
}

// Pass 2: XCD-sliced scatter. Block b: edge chunk b>>3, bucket slice b&7.
// In-side writes (edgeRec @ dense, inPrt @ piP) only when cn in slice;
// out-side write (outPrt @ poP) only when row in slice. Each XCD dirties
// only its own 1/8 of each array's line range -> L2 write coalescing.
// edgeRec = {row|col<<16, piP, poP, e} (one 16B write replaces 3 scatters).
__global__ void k_pass2(const int* __restrict__ rowI, const int* __restrict__ colI,
                        const int* __restrict__ tmpLi,
                        const int* __restrict__ inOffRaw, const int* __restrict__ pinOff,
                        const int* __restrict__ poutOff,
                        int4* __restrict__ edgeRec,
                        unsigned short* __restrict__ inPrt,
                        unsigned short* __restrict__ outPrt) {
    unsigned b = blockIdx.x;
    unsigned slice = b & (SLICES - 1);
    unsigned e = (b >> 3) * 256 + threadIdx.x;
    if (e >= N_EDGES) return;
    int r = rowI[e], cn = colI[e];
    int li = tmpLi[e];
    int liIn  = li & 0xFFFF;
    int liOut = (int)(((unsigned)li) >> 16);
    unsigned lo = slice * BUCKS_PER_SLICE;
    if ((unsigned)(cn - lo) < BUCKS_PER_SLICE) {
        int dense = inOffRaw[cn] + liIn;
        int piP   = pinOff[cn] + liIn;
        int poP   = poutOff[r] + liOut;
        edgeRec[dense] = make_int4(r | (cn << 16), piP, poP, (int)e);
        inPrt[piP] = (unsigned short)r;
    }
    if ((unsigned)(r - lo) < BUCKS_PER_SLICE) {
        int poP = poutOff[r] + liOut;
        outPrt[poP] = (unsigned short)cn;
    }
}

// ---------------- per-iteration kernels ----------------

// Fused 5-plane LDS-staged GEMM (320 threads): block stages 32 contiguous m-rows
// into LDS, each thread owns one of 160 output cols (u|v|p|q|r, all fp16) with
// wcol[36] register-resident; 2 row-groups x 16 rows.
__global__ void k_gemm5(const float* __restrict__ m,
                        const float* __restrict__ eW1, const float* __restrict__ nW1,
                        __half* __restrict__ u, __half* __restrict__ v,
                        __half* __restrict__ p, __half* __restrict__ q,
                        __half* __restrict__ r) {
    constexpr int RPB = 32;
    __shared__ float sm[RPB * HI];        // 4.6 KB
    unsigned tid = threadIdx.x;           // 320
    unsigned r0  = blockIdx.x * RPB;
    {
        const float4* gsrc = reinterpret_cast<const float4*>(m + (size_t)r0 * HI);
        float4* ldst = reinterpret_cast<float4*>(sm);
        for (unsigned i = tid; i < RPB * HI / 4; i += 320) ldst[i] = gsrc[i];
    }
    unsigned o = tid % 160, grp = tid / 160;   // grp in {0,1}
    unsigned sub = o >> 5, oo = o & 31;
    const float* W = (sub == 0) ? eW1 : (sub == 1) ? eW1 + 36 * 32 :
                     (sub == 2) ? nW1 : (sub == 3) ? nW1 + 36 * 32 : nW1 + 72 * 32;
    __half* dsth   = (sub == 0) ? u : (sub == 1) ? v : (sub == 2) ? p :
                     (sub == 3) ? q : r;
    float wcol[36];
#pragma unroll
    for (int k = 0; k < 36; ++k) wcol[k] = W[k * 32 + oo];
    __syncthreads();
#pragma unroll
    for (int i = 0; i < 16; ++i) {
        unsigned rloc = grp * 16 + i;
        const float4* mv4 = reinterpret_cast<const float4*>(sm + rloc * HI);
        float acc = 0.f;
#pragma unroll
        for (int t = 0; t < 9; ++t) {
            float4 mv = mv4[t];
            acc += mv.x * wcol[4 * t + 0];
            acc += mv.y * wcol[4 * t + 1];
            acc += mv.z * wcol[4 * t + 2];
            acc += mv.w * wcol[4 * t + 3];
        }
        dsth[(size_t)(r0 + rloc) * 32 + oo] = __float2half_rn(acc);
    }
}

// Final-pass projection: u|v only (LDS-staged, 256 threads).
__global__ void k_gemm2(const float* __restrict__ m, const float* __restrict__ W0,
                        const float* __restrict__ W1,
                        __half* __restrict__ o0, __half* __restrict__ o1) {
    constexpr int RPB = 32;
    __shared__ float sm[RPB * HI];
    unsigned tid = threadIdx.x;
    unsigned r0  = blockIdx.x * RPB;
    {
        const float4* gsrc = reinterpret_cast<const float4*>(m + (size_t)r0 * HI);
        float4* ldst = reinterpret_cast<float4*>(sm);
        for (unsigned i = tid; i < RPB * HI / 4; i += 256) ldst[i] = gsrc[i];
    }
    unsigned o = tid % 64, grp = tid / 64;     // 4 row-groups of 8
    unsigned sub = o >> 5, oo = o & 31;
    const float* W = sub ? W1 : W0;
    __half* dst    = sub ? o1 : o0;
    float wcol[36];
#pragma unroll
    for (int k = 0; k < 36; ++k) wcol[k] = W[k * 32 + oo];
    __syncthreads();
#pragma unroll
    for (int i = 0; i < 8; ++i) {
        unsigned rloc = grp * 8 + i;
        const float4* mv4 = reinterpret_cast<const float4*>(sm + rloc * HI);
        float acc = 0.f;
#pragma unroll
        for (int t = 0; t < 9; ++t) {
            float4 mv = mv4[t];
            acc += mv.x * wcol[4 * t + 0];
            acc += mv.y * wcol[4 * t + 1];
            acc += mv.z * wcol[4 * t + 2];
            acc += mv.w * wcol[4 * t + 3];
        }
        dst[(size_t)(r0 + rloc) * 32 + oo] = __float2half_rn(acc);
    }
}

// Edges in in-CSR order (grouped by col -> u side L1-resident).
// Per (idx,c): s = tanh(sum_o tanh(u[col]+v[row]+b1)*w2 + b2); softmax over c (4 lanes).
// ea outputs stored TRANSPOSED: ea[c*PADCAP + slot] (16B-contiguous per class for k_node).
template <bool FINAL>
__global__ void k_edge(const int4* __restrict__ edgeRec,
                       const __half* __restrict__ u, const __half* __restrict__ v,
                       const float* __restrict__ b1, const float* __restrict__ w2,
                       const float* __restrict__ b2,
                       __half* __restrict__ eaIn, __half* __restrict__ eaOut,
                       float* __restrict__ dst) {
    unsigned g   = blockIdx.x * 256 + threadIdx.x;   // exact grid: E*4
    unsigned c   = g & 3;
    unsigned idx = g >> 2;
    int4 rec = edgeRec[idx];
    unsigned rc  = (unsigned)rec.x;
    unsigned row = rc & 0xFFFFu, col = rc >> 16;
    const float4* u4 = reinterpret_cast<const float4*>(u + (col * 4 + c) * 32);
    const float4* v4 = reinterpret_cast<const float4*>(v + (row * 4 + c) * 32);
    float t2 = b2[0];
#pragma unroll
    for (int i = 0; i < 4; ++i) {          // 4 x (16B = 8 halves)
        F4H8 U, V; U.f4 = u4[i]; V.f4 = v4[i];
#pragma unroll
        for (int jj = 0; jj < 4; ++jj) {
            float2 uf = __half22float2(U.h2[jj]);
            float2 vf = __half22float2(V.h2[jj]);
            int o = i * 8 + jj * 2;
            t2 += fast_tanh(uf.x + vf.x + b1[o])     * w2[o];
            t2 += fast_tanh(uf.y + vf.y + b1[o + 1]) * w2[o + 1];
        }
    }
    float s  = fast_tanh(t2);
    float m1 = fmaxf(s, __shfl_xor(s, 1, 4));
    float mx = fmaxf(m1, __shfl_xor(m1, 2, 4));
    float ex = __expf(s - mx);
    float sm = ex + __shfl_xor(ex, 1, 4);
    sm = sm + __shfl_xor(sm, 2, 4);
    float val = ex / sm;
    if (FINAL) {
        dst[(unsigned)rec.w * 4 + c] = val;
    } else {
        __half hv = __float2half_rn(val);
        eaIn[(size_t)c * PADCAP + (unsigned)rec.y] = hv;
        eaOut[(size_t)c * PADCAP + (unsigned)rec.z] = hv;
    }
}

// Node net, ONE WAVE PER NODE (block=64). n = blockIdx.x is an SGPR -> offset
// and prt loads scalarize; gathers keep the proven 2x128B-coalesced-per-edge
// shape. Batch metadata vectorized (prt: one uint4 of 8xu16; ea: transposed,
// one 16B load per class). Out-loop's first batch pre-issued before the
// in-loop; in-loop prefetches batch b+8. No LDS, no barrier (nW2 read direct,
// L1-resident 4KB).
__global__ void __launch_bounds__(64, 4)
k_node(float* __restrict__ m, const __half* __restrict__ rbuf,
       const __half* __restrict__ p, const __half* __restrict__ q,
       const __half* __restrict__ eaInT, const __half* __restrict__ eaOutT,
       const int* __restrict__ pinOff, const int* __restrict__ poutOff,
       const unsigned short* __restrict__ inPrt,
       const unsigned short* __restrict__ outPrt,
       const float* __restrict__ nb1,
       const float* __restrict__ nW2, const float* __restrict__ nb2) {
    unsigned lane = threadIdx.x;         // 64
    unsigned c2 = lane >> 5, k = lane & 31;
    unsigned n = blockIdx.x;
    unsigned gOff0 = c2 * 32 + k;
    unsigned gOff1 = gOff0 + 64;

    // independent loads first (issue early)
    float b1k = nb1[k];
    float h0 = __half2float(rbuf[((size_t)n * 4 + c2) * 32 + k]) + b1k;      // class c2
    float h1 = __half2float(rbuf[((size_t)n * 4 + c2 + 2) * 32 + k]) + b1k;  // class c2+2

    int bi0 = pinOff[n],  biE = pinOff[n + 1];
    int bo0 = poutOff[n], boE = poutOff[n + 1];
    __builtin_assume((bi0 & 7) == 0);
    __builtin_assume((bo0 & 7) == 0);

    auto accum = [&](const __half* __restrict__ base, uint4 prtv, uint4 e0v, uint4 e1v) {
        unsigned pr0 = prtv.x & 0xFFFFu, pr1 = prtv.x >> 16;
        unsigned pr2 = prtv.y & 0xFFFFu, pr3 = prtv.y >> 16;
        unsigned pr4 = prtv.z & 0xFFFFu, pr5 = prtv.z >> 16;
        unsigned pr6 = prtv.w & 0xFFFFu, pr7 = prtv.w >> 16;
        __half g0h[8], g1h[8];
        const __half* r0p = base + (size_t)pr0 * 128u; g0h[0] = r0p[gOff0]; g1h[0] = r0p[gOff1];
        const __half* r1p = base + (size_t)pr1 * 128u; g0h[1] = r1p[gOff0]; g1h[1] = r1p[gOff1];
        const __half* r2p = base + (size_t)pr2 * 128u; g0h[2] = r2p[gOff0]; g1h[2] = r2p[gOff1];
        const __half* r3p = base + (size_t)pr3 * 128u; g0h[3] = r3p[gOff0]; g1h[3] = r3p[gOff1];
        const __half* r4p = base + (size_t)pr4 * 128u; g0h[4] = r4p[gOff0]; g1h[4] = r4p[gOff1];
        const __half* r5p = base + (size_t)pr5 * 128u; g0h[5] = r5p[gOff0]; g1h[5] = r5p[gOff1];
        const __half* r6p = base + (size_t)pr6 * 128u; g0h[6] = r6p[gOff0]; g1h[6] = r6p[gOff1];
        const __half* r7p = base + (size_t)pr7 * 128u; g0h[7] = r7p[gOff0]; g1h[7] = r7p[gOff1];
        union { uint4 u4; __half2 h2[4]; } E0, E1;
        E0.u4 = e0v; E1.u4 = e1v;
#pragma unroll
        for (int ii = 0; ii < 4; ++ii) {
            float2 A0 = __half22float2(E0.h2[ii]);   // class c2, edges 2ii,2ii+1
            float2 A1 = __half22float2(E1.h2[ii]);   // class c2+2
            h0 += A0.x * __half2float(g0h[2 * ii]) + A0.y * __half2float(g0h[2 * ii + 1]);
            h1 += A1.x * __half2float(g1h[2 * ii]) + A1.y * __half2float(g1h[2 * ii + 1]);
        }
    };

    // pre-issue first OUT batch (hides its latency under the whole in-loop)
    uint4 oprt = {0, 0, 0, 0}, oe0 = {0, 0, 0, 0}, oe1 = {0, 0, 0, 0};
    if (bo0 < boE) {
        oprt = *(const uint4*)(outPrt + bo0);
        oe0  = *(const uint4*)(eaOutT + (size_t)c2 * PADCAP + bo0);
        oe1  = *(const uint4*)(eaOutT + (size_t)(c2 + 2) * PADCAP + bo0);
    }

    if (bi0 < biE) {
        uint4 cprt = *(const uint4*)(inPrt + bi0);
        uint4 ce0  = *(const uint4*)(eaInT + (size_t)c2 * PADCAP + bi0);
        uint4 ce1  = *(const uint4*)(eaInT + (size_t)(c2 + 2) * PADCAP + bi0);
        for (int b = bi0; b < biE; b += 8) {
            uint4 nprt = cprt, ne0 = ce0, ne1 = ce1;
            if (b + 8 < biE) {                       // prefetch next batch
                nprt = *(const uint4*)(inPrt + b + 8);
                ne0  = *(const uint4*)(eaInT + (size_t)c2 * PADCAP + b + 8);
                ne1  = *(const uint4*)(eaInT + (size_t)(c2 + 2) * PADCAP + b + 8);
            }
            accum(p, cprt, ce0, ce1);
            cprt = nprt; ce0 = ne0; ce1 = ne1;
        }
    }
    if (bo0 < boE) {
        uint4 cprt = oprt, ce0 = oe0, ce1 = oe1;     // already in flight
        for (int b = bo0; b < boE; b += 8) {
            uint4 nprt = cprt, ne0 = ce0, ne1 = ce1;
            if (b + 8 < boE) {
                nprt = *(const uint4*)(outPrt + b + 8);
                ne0  = *(const uint4*)(eaOutT + (size_t)c2 * PADCAP + b + 8);
                ne1  = *(const uint4*)(eaOutT + (size_t)(c2 + 2) * PADCAP + b + 8);
            }
            accum(q, cprt, ce0, ce1);
            cprt = nprt; ce0 = ne0; ce1 = ne1;
        }
    }

    float t0 = fast_tanh(h0);   // class c2, dim k (lane-local)
    float t1 = fast_tanh(h1);   // class c2+2, dim k
    float hh0 = nb2[k], hh1 = hh0;
#pragma unroll
    for (int kk = 0; kk < 32; ++kk) {
        float w = nW2[kk * 32 + k];                  // L1-resident broadcast
        float s0 = __shfl(t0, (int)(c2 * 32 + kk), 64);   // t(class c2, kk)
        float s1 = __shfl(t1, (int)(c2 * 32 + kk), 64);   // t(class c2+2, kk)
        hh0 += s0 * w;
        hh1 += s1 * w;
    }
    m[((size_t)n * 4 + c2) * HI + k]     = fast_tanh(hh0);
    m[((size_t)n * 4 + c2 + 2) * HI + k] = fast_tanh(hh1);
}

extern "C" void kernel_launch(void* const* d_in, const int* in_sizes, int n_in,
                              void* d_out, int out_size, void* d_ws, size_t ws_size,
                              hipStream_t stream) {
    const float* x   = (const float*)d_in[0];
    const int*   ei  = (const int*)d_in[1];
    const float* inW = (const float*)d_in[2];
    const float* inb = (const float*)d_in[3];
    const float* eW1 = (const float*)d_in[4];
    const float* eb1 = (const float*)d_in[5];
    const float* eW2 = (const float*)d_in[6];
    const float* eb2 = (const float*)d_in[7];
    const float* nW1 = (const float*)d_in[8];
    const float* nb1 = (const float*)d_in[9];
    const float* nW2 = (const float*)d_in[10];
    const float* nb2 = (const float*)d_in[11];
    float* out = (float*)d_out;

    // Workspace (~110 MB): m 28.8 | u,v,p,q,rbuf fp16 64 | eaIn/eaOut fp16 10.8
    // (transposed) | inPrt/outPrt u16 2.7 | edgeRec 6.4 | offs ~1.0
    // tmpLi (pass1->pass2 temp) aliases u (dead during CSR build).
    float*  m     = (float*)d_ws;
    __half* u     = (__half*)(m + (size_t)ROWS_P * HI);
    __half* v     = u + (size_t)ROWS_P * 32;
    __half* p     = v + (size_t)ROWS_P * 32;
    __half* q     = p + (size_t)ROWS_P * 32;
    __half* rbuf  = q + (size_t)ROWS_P * 32;
    __half* eaIn  = rbuf + (size_t)ROWS_P * 32;
    __half* eaOut = eaIn + (size_t)PADCAP * 4;
    unsigned short* inPrt  = (unsigned short*)(eaOut + (size_t)PADCAP * 4);
    unsigned short* outPrt = inPrt + PADCAP;
    int4*   edgeRec = (int4*)(outPrt + PADCAP);      // 16B-aligned by construction
    int*    inOffRaw = (int*)(edgeRec + N_EDGES);
    int*    pinOff   = inOffRaw + (N_NODES + 1);
    int*    poutOff  = pinOff + (N_NODES + 1);
    int*    inCnt    = poutOff + (N_NODES + 1);
    int*    outCnt   = inCnt + N_NODES;
    int*    tmpLi    = (int*)u;                      // aliased: dead until k_gemm5

    const int gridE = (N_EDGES + 255) / 256;
    // contiguous zero region: eaIn | eaOut | inPrt | outPrt
    const size_t zeroBytes = (size_t)PADCAP * 4 * 2 * 2 + (size_t)PADCAP * 2 * 2;

    for (int j = 0; j < 3; ++j) {
        const int*   rowI = ei + (size_t)j * 2 * N_EDGES;
        const int*   colI = rowI + N_EDGES;
        const float* eW1j = eW1 + j * 72 * 32;
        const float* eb1j = eb1 + j * 32;
        const float* eW2j = eW2 + j * 32;
        const float* eb2j = eb2 + j;
        const float* nW1j = nW1 + j * 108 * 32;
        const float* nb1j = nb1 + j * 32;
        const float* nW2j = nW2 + j * 1024;
        const float* nb2j = nb2 + j * 32;

        // CSR build (padded): 1 atomic pass + scan + XCD-sliced scatter
        hipMemsetAsync(inCnt, 0, 2 * N_NODES * sizeof(int), stream);
        hipMemsetAsync(eaIn, 0, zeroBytes, stream);
        k_pass1<<<gridE, 256, 0, stream>>>(rowI, colI, inCnt, outCnt, tmpLi);
        k_scan<<<3, 1024, 0, stream>>>(inCnt, outCnt, inOffRaw, pinOff, poutOff);
        k_pass2<<<gridE * SLICES, 256, 0, stream>>>(rowI, colI, tmpLi,
                                                    inOffRaw, pinOff, poutOff,
                                                    edgeRec, inPrt, outPrt);

        k_init<<<(N_NODES * HI + 255) / 256, 256, 0, stream>>>(
            x + (size_t)j * N_NODES * 4, inW + j * 128, inb + j * 32, m);

        for (int it = 0; it < 3; ++it) {
            k_gemm5<<<ROWS_P / 32, 320, 0, stream>>>(m, eW1j, nW1j, u, v, p, q, rbuf);
            k_edge<false><<<N_EDGES * 4 / 256, 256, 0, stream>>>(
                edgeRec, u, v, eb1j, eW2j, eb2j, eaIn, eaOut, nullptr);
            k_node<<<N_NODES, 64, 0, stream>>>(m, rbuf, p, q, eaIn, eaOut,
                                               pinOff, poutOff, inPrt, outPrt,
                                               nb1j, nW2j, nb2j);
        }
        k_gemm2<<<ROWS_P / 32, 256, 0, stream>>>(m, eW1j, eW1j + 36 * 32, u, v);
        k_edge<true><<<N_EDGES * 4 / 256, 256, 0, stream>>>(
            edgeRec, u, v, eb1j, eW2j, eb2j, nullptr, nullptr,
            out + (size_t)j * N_EDGES * 4);
    }
}